// Round 1
// baseline (2288.910 us; speedup 1.0000x reference)
//
#include <hip/hip_runtime.h>
#include <cstdio>

#define E_DIM 512
#define L_DIM 4096
#define B_DIM 8
#define H_DIM 8
#define T_DIM 2
#define M_ROWS (B_DIM * L_DIM)  // 32768

// ---------------------------------------------------------------------------
// sin/cos positional tables: idx = (pi/2)*(i+1)/L
// ---------------------------------------------------------------------------
__global__ void sincos_kernel(float* __restrict__ sintab, float* __restrict__ costab) {
  int i = blockIdx.x * blockDim.x + threadIdx.x;
  if (i < L_DIM) {
    float idx = 1.57079632679489662f * (float)(i + 1) / (float)L_DIM;
    sintab[i] = sinf(idx);
    costab[i] = cosf(idx);
  }
}

// ---------------------------------------------------------------------------
// Y[M][512] = X[M][512] @ W[512][512]^T + bias   (fp32, tiled 128x128, 8x8/thr)
// ---------------------------------------------------------------------------
__global__ __launch_bounds__(256) void gemm_xwt_f32(
    const float* __restrict__ X, const float* __restrict__ W,
    const float* __restrict__ bias, float* __restrict__ Y) {
  __shared__ float As[16][132];  // [k][m], +4 pad
  __shared__ float Bs[16][132];  // [k][n]
  const int tid = threadIdx.x;
  const int m0 = blockIdx.x * 128;
  const int n0 = blockIdx.y * 128;
  const int tm = tid & 15;
  const int tn = tid >> 4;
  float acc[8][8];
#pragma unroll
  for (int i = 0; i < 8; ++i)
#pragma unroll
    for (int j = 0; j < 8; ++j) acc[i][j] = 0.f;

  for (int k0 = 0; k0 < 512; k0 += 16) {
#pragma unroll
    for (int i = 0; i < 2; ++i) {
      int idx = tid + i * 256;     // 0..511
      int r = idx >> 2;            // row 0..127
      int c4 = (idx & 3) * 4;      // k sub-offset
      float4 va = *(const float4*)(X + (size_t)(m0 + r) * 512 + k0 + c4);
      As[c4 + 0][r] = va.x; As[c4 + 1][r] = va.y;
      As[c4 + 2][r] = va.z; As[c4 + 3][r] = va.w;
      float4 vb = *(const float4*)(W + (size_t)(n0 + r) * 512 + k0 + c4);
      Bs[c4 + 0][r] = vb.x; Bs[c4 + 1][r] = vb.y;
      Bs[c4 + 2][r] = vb.z; Bs[c4 + 3][r] = vb.w;
    }
    __syncthreads();
#pragma unroll
    for (int k = 0; k < 16; ++k) {
      float a[8], b[8];
      *(float4*)&a[0] = *(const float4*)&As[k][tm * 8];
      *(float4*)&a[4] = *(const float4*)&As[k][tm * 8 + 4];
      *(float4*)&b[0] = *(const float4*)&Bs[k][tn * 8];
      *(float4*)&b[4] = *(const float4*)&Bs[k][tn * 8 + 4];
#pragma unroll
      for (int i = 0; i < 8; ++i)
#pragma unroll
        for (int j = 0; j < 8; ++j)
          acc[i][j] = fmaf(a[i], b[j], acc[i][j]);
    }
    __syncthreads();
  }
  float bb[8];
  *(float4*)&bb[0] = *(const float4*)&bias[n0 + tn * 8];
  *(float4*)&bb[4] = *(const float4*)&bias[n0 + tn * 8 + 4];
#pragma unroll
  for (int i = 0; i < 8; ++i) {
    size_t row = (size_t)(m0 + tm * 8 + i) * 512 + n0 + tn * 8;
    float4 o0, o1;
    o0.x = acc[i][0] + bb[0]; o0.y = acc[i][1] + bb[1];
    o0.z = acc[i][2] + bb[2]; o0.w = acc[i][3] + bb[3];
    o1.x = acc[i][4] + bb[4]; o1.y = acc[i][5] + bb[5];
    o1.z = acc[i][6] + bb[6]; o1.w = acc[i][7] + bb[7];
    *(float4*)(Y + row) = o0;
    *(float4*)(Y + row + 4) = o1;
  }
}

// ---------------------------------------------------------------------------
// k softmax column stats (over s=4096) per (b, f): online max + sum(exp)
// blockDim (64 f, 4 s-strips); grid (8 f-tiles, 8 b)
// ---------------------------------------------------------------------------
__global__ __launch_bounds__(256) void kcolstats_kernel(
    const float* __restrict__ Kp, float* __restrict__ colmax,
    float* __restrict__ colinv) {
  int b = blockIdx.y;
  int tx = threadIdx.x;
  int f = blockIdx.x * 64 + tx;
  int sy = threadIdx.y;
  const float* p = Kp + (size_t)b * L_DIM * E_DIM + f;
  float m = -3.0e38f, sum = 0.f;
  for (int s = sy; s < L_DIM; s += 4) {
    float v = p[(size_t)s * E_DIM];
    float nm = fmaxf(m, v);
    sum = sum * __expf(m - nm) + __expf(v - nm);
    m = nm;
  }
  __shared__ float sm[4][64];
  __shared__ float ss[4][64];
  sm[sy][tx] = m;
  ss[sy][tx] = sum;
  __syncthreads();
  if (sy == 0) {
    float M = sm[0][tx];
    float S = ss[0][tx];
#pragma unroll
    for (int i = 1; i < 4; ++i) {
      float mi = sm[i][tx];
      float nm = fmaxf(M, mi);
      S = S * __expf(M - nm) + ss[i][tx] * __expf(mi - nm);
      M = nm;
    }
    colmax[b * E_DIM + f] = M;
    colinv[b * E_DIM + f] = 1.f / S;
  }
}

// ---------------------------------------------------------------------------
// kv partials: kvpart[chunk][n][dd][m] = sum_{s in chunk} k2[n,s,dd] * v[n,s,m]
// grid (8 s-chunks of 512, 64 n); 256 thr: d = tid&63 (dd=d sin, d+64 cos),
// m-group = (tid>>6)*16
// ---------------------------------------------------------------------------
__global__ __launch_bounds__(256) void kv_partial_kernel(
    const float* __restrict__ Kp, const float* __restrict__ Vp,
    const float* __restrict__ colmax, const float* __restrict__ colinv,
    const float* __restrict__ sintab, const float* __restrict__ costab,
    float* __restrict__ kvpart) {
  int chunk = blockIdx.x;
  int n = blockIdx.y;
  int b = n >> 3, h = n & 7;
  __shared__ float ks[64][64];
  __shared__ float vs[64][64];
  __shared__ float cmaxs[64], cinvs[64];
  int tid = threadIdx.x;
  if (tid < 64) {
    cmaxs[tid] = colmax[b * E_DIM + h * 64 + tid];
    cinvs[tid] = colinv[b * E_DIM + h * 64 + tid];
  }
  __syncthreads();
  int d = tid & 63;
  int mg = (tid >> 6) * 16;
  float accS[16], accC[16];
#pragma unroll
  for (int j = 0; j < 16; ++j) { accS[j] = 0.f; accC[j] = 0.f; }
  int sbase = chunk * 512;
  for (int sc = 0; sc < 512; sc += 64) {
#pragma unroll
    for (int i = 0; i < 4; ++i) {
      int idx = tid + i * 256;   // 0..1023
      int sl = idx >> 4;
      int c4 = (idx & 15) * 4;
      int s = sbase + sc + sl;
      float4 kx = *(const float4*)(Kp + ((size_t)b * L_DIM + s) * E_DIM + h * 64 + c4);
      float4 ko;
      ko.x = __expf(kx.x - cmaxs[c4 + 0]) * cinvs[c4 + 0];
      ko.y = __expf(kx.y - cmaxs[c4 + 1]) * cinvs[c4 + 1];
      ko.z = __expf(kx.z - cmaxs[c4 + 2]) * cinvs[c4 + 2];
      ko.w = __expf(kx.w - cmaxs[c4 + 3]) * cinvs[c4 + 3];
      *(float4*)&ks[sl][c4] = ko;
      // torch-faithful v permutation: row = Vproj[s>>9][((s&511)<<3)|b][h*64+...]
      int vrow = ((s & 511) << 3) | b;
      float4 vx = *(const float4*)(Vp + ((size_t)(s >> 9) * L_DIM + vrow) * E_DIM + h * 64 + c4);
      *(float4*)&vs[sl][c4] = vx;
    }
    __syncthreads();
#pragma unroll 4
    for (int sl = 0; sl < 64; ++sl) {
      int s = sbase + sc + sl;
      float kk = ks[sl][d];
      float sv = kk * sintab[s];
      float cv = kk * costab[s];
#pragma unroll
      for (int j4 = 0; j4 < 16; j4 += 4) {
        float4 vv = *(const float4*)&vs[sl][mg + j4];
        accS[j4 + 0] = fmaf(sv, vv.x, accS[j4 + 0]);
        accS[j4 + 1] = fmaf(sv, vv.y, accS[j4 + 1]);
        accS[j4 + 2] = fmaf(sv, vv.z, accS[j4 + 2]);
        accS[j4 + 3] = fmaf(sv, vv.w, accS[j4 + 3]);
        accC[j4 + 0] = fmaf(cv, vv.x, accC[j4 + 0]);
        accC[j4 + 1] = fmaf(cv, vv.y, accC[j4 + 1]);
        accC[j4 + 2] = fmaf(cv, vv.z, accC[j4 + 2]);
        accC[j4 + 3] = fmaf(cv, vv.w, accC[j4 + 3]);
      }
    }
    __syncthreads();
  }
  float* op = kvpart + (((size_t)chunk * 64 + n) * 128 + d) * 64 + mg;
#pragma unroll
  for (int j4 = 0; j4 < 16; j4 += 4) {
    *(float4*)(op + j4) = make_float4(accS[j4], accS[j4 + 1], accS[j4 + 2], accS[j4 + 3]);
    *(float4*)(op + 64 * 64 + j4) = make_float4(accC[j4], accC[j4 + 1], accC[j4 + 2], accC[j4 + 3]);
  }
}

__global__ void kv_reduce_kernel(const float* __restrict__ part, float* __restrict__ kv) {
  int i = blockIdx.x * 256 + threadIdx.x;  // 64*128*64 elements
  float s = 0.f;
#pragma unroll
  for (int c = 0; c < 8; ++c) s += part[(size_t)c * (64 * 128 * 64) + i];
  kv[i] = s;
}

// ---------------------------------------------------------------------------
// out2[b][l][h*64+m] += sum_dd q2[t,n,l,dd]*kv[t,n,dd,m]
// q-softmax over d + sin/cos fused into LDS staging.
// grid (64 l-chunks of 64, 64 n); 256 thr
// ---------------------------------------------------------------------------
__global__ __launch_bounds__(256) void out_accum_kernel(
    const float* __restrict__ Qp, const float* __restrict__ kv,
    const float* __restrict__ sintab, const float* __restrict__ costab,
    float* __restrict__ out2) {
  int lc = blockIdx.x;
  int n = blockIdx.y;
  int b = n >> 3, h = n & 7;
  __shared__ float q2s[128][68];  // [dd][lw], pad 68
  __shared__ float kvs[128][64];  // [dd][m]
  int tid = threadIdx.x;
  const float* kvn = kv + (size_t)n * 128 * 64;
#pragma unroll
  for (int i = 0; i < 8; ++i) {
    int idx = tid + i * 256;  // f4 idx 0..2047
    int dd = idx >> 4;
    int c4 = (idx & 15) * 4;
    *(float4*)&kvs[dd][c4] = *(const float4*)(kvn + (size_t)idx * 4);
  }
  int lane = tid & 63;
  int w = tid >> 6;
  int l0 = lc * 64;
  for (int i = 0; i < 16; ++i) {
    int lw = w + i * 4;
    int l = l0 + lw;
    float x = Qp[((size_t)b * L_DIM + l) * E_DIM + h * 64 + lane];
    float m = x;
#pragma unroll
    for (int off = 32; off > 0; off >>= 1) m = fmaxf(m, __shfl_xor(m, off));
    float e = __expf(x - m);
    float ssum = e;
#pragma unroll
    for (int off = 32; off > 0; off >>= 1) ssum += __shfl_xor(ssum, off);
    float p = e / ssum;
    q2s[lane][lw] = p * sintab[l];
    q2s[lane + 64][lw] = p * costab[l];
  }
  __syncthreads();
  int tl = tid >> 4;  // rows tl*4..+3
  int tm = tid & 15;  // cols tm*4..+3
  float acc[4][4];
#pragma unroll
  for (int i = 0; i < 4; ++i)
#pragma unroll
    for (int j = 0; j < 4; ++j) acc[i][j] = 0.f;
#pragma unroll 4
  for (int dd = 0; dd < 128; ++dd) {
    float4 a = *(const float4*)&q2s[dd][tl * 4];
    float4 bv = *(const float4*)&kvs[dd][tm * 4];
    acc[0][0] = fmaf(a.x, bv.x, acc[0][0]); acc[0][1] = fmaf(a.x, bv.y, acc[0][1]);
    acc[0][2] = fmaf(a.x, bv.z, acc[0][2]); acc[0][3] = fmaf(a.x, bv.w, acc[0][3]);
    acc[1][0] = fmaf(a.y, bv.x, acc[1][0]); acc[1][1] = fmaf(a.y, bv.y, acc[1][1]);
    acc[1][2] = fmaf(a.y, bv.z, acc[1][2]); acc[1][3] = fmaf(a.y, bv.w, acc[1][3]);
    acc[2][0] = fmaf(a.z, bv.x, acc[2][0]); acc[2][1] = fmaf(a.z, bv.y, acc[2][1]);
    acc[2][2] = fmaf(a.z, bv.z, acc[2][2]); acc[2][3] = fmaf(a.z, bv.w, acc[2][3]);
    acc[3][0] = fmaf(a.w, bv.x, acc[3][0]); acc[3][1] = fmaf(a.w, bv.y, acc[3][1]);
    acc[3][2] = fmaf(a.w, bv.z, acc[3][2]); acc[3][3] = fmaf(a.w, bv.w, acc[3][3]);
  }
#pragma unroll
  for (int i = 0; i < 4; ++i) {
    int l = l0 + tl * 4 + i;
    float* op = out2 + ((size_t)b * L_DIM + l) * E_DIM + h * 64 + tm * 4;
    float4 cur = *(float4*)op;
    cur.x += acc[i][0]; cur.y += acc[i][1]; cur.z += acc[i][2]; cur.w += acc[i][3];
    *(float4*)op = cur;
  }
}

// ---------------------------------------------------------------------------
extern "C" void kernel_launch(void* const* d_in, const int* in_sizes, int n_in,
                              void* d_out, int out_size, void* d_ws, size_t ws_size,
                              hipStream_t stream) {
  const float* query = (const float*)d_in[0];
  const float* key   = (const float*)d_in[1];
  const float* value = (const float*)d_in[2];
  const float* Wq    = (const float*)d_in[3];
  const float* bq    = (const float*)d_in[4];
  const float* Wk    = (const float*)d_in[5];
  const float* bk    = (const float*)d_in[6];
  const float* Wv    = (const float*)d_in[7];
  const float* bv    = (const float*)d_in[8];
  const float* Wout  = (const float*)d_in[9];
  const float* bout  = (const float*)d_in[10];
  float* out = (float*)d_out;
  float* ws = (float*)d_ws;

  const size_t F_PROJ   = 0;                      // 16.78M floats (kproj then qproj, per t)
  const size_t F_VOUT   = F_PROJ + 16777216;      // vproj, later reused as out2
  const size_t F_KVPART = F_VOUT + 16777216;      // 8*64*128*64
  const size_t F_KV     = F_KVPART + 4194304;     // kv[2][64][128][64]
  const size_t F_CMAX   = F_KV + 1048576;
  const size_t F_CINV   = F_CMAX + 4096;
  const size_t F_SIN    = F_CINV + 4096;
  const size_t F_COS    = F_SIN + 4096;
  const size_t TOTALF   = F_COS + 4096;
  if (ws_size < TOTALF * sizeof(float)) {
    fprintf(stderr, "kernel_launch: ws too small (%zu < %zu)\n", ws_size, TOTALF * 4);
    return;
  }
  float* proj   = ws + F_PROJ;
  float* vout   = ws + F_VOUT;
  float* kvpart = ws + F_KVPART;
  float* kvbuf  = ws + F_KV;
  float* cmax   = ws + F_CMAX;
  float* cinv   = ws + F_CINV;
  float* sintab = ws + F_SIN;
  float* costab = ws + F_COS;

  sincos_kernel<<<16, 256, 0, stream>>>(sintab, costab);

  dim3 gemm_grid(M_ROWS / 128, 4);
  // V projection
  gemm_xwt_f32<<<gemm_grid, 256, 0, stream>>>(value, Wv, bv, vout);

  // per-term: K-projection -> col softmax stats -> kv state
  for (int t = 0; t < T_DIM; ++t) {
    gemm_xwt_f32<<<gemm_grid, 256, 0, stream>>>(key, Wk + (size_t)t * 512 * 512,
                                                bk + t * 512, proj);
    kcolstats_kernel<<<dim3(8, 8), dim3(64, 4), 0, stream>>>(proj, cmax, cinv);
    kv_partial_kernel<<<dim3(8, 64), 256, 0, stream>>>(proj, vout, cmax, cinv,
                                                       sintab, costab, kvpart);
    kv_reduce_kernel<<<2048, 256, 0, stream>>>(kvpart, kvbuf + (size_t)t * 524288);
  }
  // vproj dead; region becomes out2 accumulator
  hipMemsetAsync(vout, 0, 16777216 * sizeof(float), stream);
  for (int t = 0; t < T_DIM; ++t) {
    gemm_xwt_f32<<<gemm_grid, 256, 0, stream>>>(query, Wq + (size_t)t * 512 * 512,
                                                bq + t * 512, proj);
    out_accum_kernel<<<dim3(64, 64), 256, 0, stream>>>(proj, kvbuf + (size_t)t * 524288,
                                                       sintab, costab, vout);
  }
  // final output projection
  gemm_xwt_f32<<<gemm_grid, 256, 0, stream>>>(vout, Wout, bout, out);
}

// Round 2
// 830.133 us; speedup vs baseline: 2.7573x; 2.7573x over previous
//
#include <hip/hip_runtime.h>
#include <cstdio>

#define E_DIM 512
#define L_DIM 4096
#define B_DIM 8
#define H_DIM 8
#define T_DIM 2
#define M_ROWS (B_DIM * L_DIM)  // 32768

typedef __attribute__((ext_vector_type(8))) unsigned short u16x8;
typedef __attribute__((ext_vector_type(8))) __bf16 bf16x8;
typedef __attribute__((ext_vector_type(4))) float f32x4;

static __device__ inline unsigned short f2bf(float f) {
  unsigned int u = __float_as_uint(f);
  unsigned int r = (u + 0x7FFFu + ((u >> 16) & 1u)) >> 16;
  return (unsigned short)r;
}

// ---------------------------------------------------------------------------
// sin/cos positional tables: idx = (pi/2)*(i+1)/L
// ---------------------------------------------------------------------------
__global__ void sincos_kernel(float* __restrict__ sintab, float* __restrict__ costab) {
  int i = blockIdx.x * blockDim.x + threadIdx.x;
  if (i < L_DIM) {
    float idx = 1.57079632679489662f * (float)(i + 1) / (float)L_DIM;
    sintab[i] = sinf(idx);
    costab[i] = cosf(idx);
  }
}

// ---------------------------------------------------------------------------
// Y[M][512] = X[M][512] @ W[512][512]^T + bias
// fp32 in/out, bf16 MFMA compute. 128x128 tile, BK=64, 4 waves (2x2),
// per-wave 64x64 = 4x4 frags of 16x16x32. LDS XOR-swizzled (T2-style).
// ---------------------------------------------------------------------------
__global__ __launch_bounds__(256) void gemm_xwt_bf16(
    const float* __restrict__ X, const float* __restrict__ W,
    const float* __restrict__ bias, float* __restrict__ Y) {
  __shared__ __align__(16) unsigned short As[128 * 64];
  __shared__ __align__(16) unsigned short Bs[128 * 64];
  const int tid = threadIdx.x;
  const int m0 = blockIdx.x * 128;
  const int n0 = blockIdx.y * 128;
  const int lane = tid & 63;
  const int w = tid >> 6;
  const int wr = w >> 1, wc = w & 1;
  const int lr = lane & 15;
  const int lk = (lane >> 4) * 8;

  f32x4 acc[4][4];
#pragma unroll
  for (int i = 0; i < 4; ++i)
#pragma unroll
    for (int j = 0; j < 4; ++j) acc[i][j] = (f32x4){0.f, 0.f, 0.f, 0.f};

  for (int k0 = 0; k0 < 512; k0 += 64) {
    // each thread stages 4 chunks of 8 floats for A and for B
    float4 va[4][2], vb[4][2];
#pragma unroll
    for (int i = 0; i < 4; ++i) {
      int idx = tid + i * 256;        // 0..1023
      int r = idx >> 3;               // 0..127
      int c8 = (idx & 7) * 8;         // 0..56
      const float* pa = X + (size_t)(m0 + r) * 512 + k0 + c8;
      va[i][0] = *(const float4*)pa;
      va[i][1] = *(const float4*)(pa + 4);
      const float* pb = W + (size_t)(n0 + r) * 512 + k0 + c8;
      vb[i][0] = *(const float4*)pb;
      vb[i][1] = *(const float4*)(pb + 4);
    }
    __syncthreads();  // previous iteration's LDS reads complete
#pragma unroll
    for (int i = 0; i < 4; ++i) {
      int idx = tid + i * 256;
      int r = idx >> 3;
      int c8 = (idx & 7) * 8;
      int off = r * 64 + (c8 ^ ((r & 7) << 3));  // element-offset XOR swizzle (16B granules)
      float ta[8], tb[8];
      *(float4*)&ta[0] = va[i][0]; *(float4*)&ta[4] = va[i][1];
      *(float4*)&tb[0] = vb[i][0]; *(float4*)&tb[4] = vb[i][1];
      u16x8 oa, ob;
#pragma unroll
      for (int j = 0; j < 8; ++j) { oa[j] = f2bf(ta[j]); ob[j] = f2bf(tb[j]); }
      *(u16x8*)&As[off] = oa;
      *(u16x8*)&Bs[off] = ob;
    }
    __syncthreads();
#pragma unroll
    for (int kk = 0; kk < 2; ++kk) {
      bf16x8 av[4], bv[4];
      int ke = kk * 32 + lk;
#pragma unroll
      for (int fm = 0; fm < 4; ++fm) {
        int row = wr * 64 + fm * 16 + lr;
        av[fm] = *(const bf16x8*)&As[row * 64 + (ke ^ ((row & 7) << 3))];
      }
#pragma unroll
      for (int fn = 0; fn < 4; ++fn) {
        int row = wc * 64 + fn * 16 + lr;
        bv[fn] = *(const bf16x8*)&Bs[row * 64 + (ke ^ ((row & 7) << 3))];
      }
#pragma unroll
      for (int fm = 0; fm < 4; ++fm)
#pragma unroll
        for (int fn = 0; fn < 4; ++fn)
          acc[fm][fn] = __builtin_amdgcn_mfma_f32_16x16x32_bf16(av[fm], bv[fn],
                                                                acc[fm][fn], 0, 0, 0);
    }
  }
  // epilogue: C/D mapping col=lane&15, row=(lane>>4)*4+reg
  const int rq = lane >> 4;
#pragma unroll
  for (int fn = 0; fn < 4; ++fn) {
    int col = n0 + wc * 64 + fn * 16 + lr;
    float bb = bias[col];
#pragma unroll
    for (int fm = 0; fm < 4; ++fm) {
      int rbase = m0 + wr * 64 + fm * 16 + rq * 4;
#pragma unroll
      for (int j = 0; j < 4; ++j)
        Y[(size_t)(rbase + j) * 512 + col] = acc[fm][fn][j] + bb;
    }
  }
}

// ---------------------------------------------------------------------------
// k softmax column stats, phase 1: per 128-row s-chunk partial max/sum(exp)
// grid (8 f-tiles, 8 b, 32 chunks), block (64 f, 4 s-strips)
// ---------------------------------------------------------------------------
__global__ __launch_bounds__(256) void kcolstats_part(
    const float* __restrict__ Kp, float* __restrict__ pmax,
    float* __restrict__ psum) {
  int b = blockIdx.y;
  int chunk = blockIdx.z;
  int tx = threadIdx.x;
  int f = blockIdx.x * 64 + tx;
  int sy = threadIdx.y;
  const float* p = Kp + ((size_t)b * L_DIM + chunk * 128) * E_DIM + f;
  float m = -3.0e38f, sum = 0.f;
  for (int s = sy; s < 128; s += 4) {
    float v = p[(size_t)s * E_DIM];
    float nm = fmaxf(m, v);
    sum = sum * __expf(m - nm) + __expf(v - nm);
    m = nm;
  }
  __shared__ float sm[4][64];
  __shared__ float ss[4][64];
  sm[sy][tx] = m;
  ss[sy][tx] = sum;
  __syncthreads();
  if (sy == 0) {
    float M = sm[0][tx];
    float S = ss[0][tx];
#pragma unroll
    for (int i = 1; i < 4; ++i) {
      float mi = sm[i][tx];
      float nm = fmaxf(M, mi);
      S = S * __expf(M - nm) + ss[i][tx] * __expf(mi - nm);
      M = nm;
    }
    pmax[(size_t)chunk * 4096 + b * E_DIM + f] = M;
    psum[(size_t)chunk * 4096 + b * E_DIM + f] = S;
  }
}

// phase 2: reduce the 32 chunks
__global__ void kcolstats_reduce(const float* __restrict__ pmax,
                                 const float* __restrict__ psum,
                                 float* __restrict__ colmax,
                                 float* __restrict__ colinv) {
  int i = blockIdx.x * 256 + threadIdx.x;  // 0..4095 = b*512+f
  float M = -3.0e38f, S = 0.f;
#pragma unroll
  for (int c = 0; c < 32; ++c) {
    float m = pmax[(size_t)c * 4096 + i];
    float s = psum[(size_t)c * 4096 + i];
    float nm = fmaxf(M, m);
    S = S * __expf(M - nm) + s * __expf(m - nm);
    M = nm;
  }
  colmax[i] = M;
  colinv[i] = 1.f / S;
}

// ---------------------------------------------------------------------------
// kv partials: kvpart[chunk][n][dd][m] = sum_{s in chunk} k2[n,s,dd] * v[n,s,m]
// ---------------------------------------------------------------------------
__global__ __launch_bounds__(256) void kv_partial_kernel(
    const float* __restrict__ Kp, const float* __restrict__ Vp,
    const float* __restrict__ colmax, const float* __restrict__ colinv,
    const float* __restrict__ sintab, const float* __restrict__ costab,
    float* __restrict__ kvpart) {
  int chunk = blockIdx.x;
  int n = blockIdx.y;
  int b = n >> 3, h = n & 7;
  __shared__ float ks[64][64];
  __shared__ float vs[64][64];
  __shared__ float cmaxs[64], cinvs[64];
  int tid = threadIdx.x;
  if (tid < 64) {
    cmaxs[tid] = colmax[b * E_DIM + h * 64 + tid];
    cinvs[tid] = colinv[b * E_DIM + h * 64 + tid];
  }
  __syncthreads();
  int d = tid & 63;
  int mg = (tid >> 6) * 16;
  float accS[16], accC[16];
#pragma unroll
  for (int j = 0; j < 16; ++j) { accS[j] = 0.f; accC[j] = 0.f; }
  int sbase = chunk * 512;
  for (int sc = 0; sc < 512; sc += 64) {
#pragma unroll
    for (int i = 0; i < 4; ++i) {
      int idx = tid + i * 256;
      int sl = idx >> 4;
      int c4 = (idx & 15) * 4;
      int s = sbase + sc + sl;
      float4 kx = *(const float4*)(Kp + ((size_t)b * L_DIM + s) * E_DIM + h * 64 + c4);
      float4 ko;
      ko.x = __expf(kx.x - cmaxs[c4 + 0]) * cinvs[c4 + 0];
      ko.y = __expf(kx.y - cmaxs[c4 + 1]) * cinvs[c4 + 1];
      ko.z = __expf(kx.z - cmaxs[c4 + 2]) * cinvs[c4 + 2];
      ko.w = __expf(kx.w - cmaxs[c4 + 3]) * cinvs[c4 + 3];
      *(float4*)&ks[sl][c4] = ko;
      int vrow = ((s & 511) << 3) | b;
      float4 vx = *(const float4*)(Vp + ((size_t)(s >> 9) * L_DIM + vrow) * E_DIM + h * 64 + c4);
      *(float4*)&vs[sl][c4] = vx;
    }
    __syncthreads();
#pragma unroll 4
    for (int sl = 0; sl < 64; ++sl) {
      int s = sbase + sc + sl;
      float kk = ks[sl][d];
      float sv = kk * sintab[s];
      float cv = kk * costab[s];
#pragma unroll
      for (int j4 = 0; j4 < 16; j4 += 4) {
        float4 vv = *(const float4*)&vs[sl][mg + j4];
        accS[j4 + 0] = fmaf(sv, vv.x, accS[j4 + 0]);
        accS[j4 + 1] = fmaf(sv, vv.y, accS[j4 + 1]);
        accS[j4 + 2] = fmaf(sv, vv.z, accS[j4 + 2]);
        accS[j4 + 3] = fmaf(sv, vv.w, accS[j4 + 3]);
        accC[j4 + 0] = fmaf(cv, vv.x, accC[j4 + 0]);
        accC[j4 + 1] = fmaf(cv, vv.y, accC[j4 + 1]);
        accC[j4 + 2] = fmaf(cv, vv.z, accC[j4 + 2]);
        accC[j4 + 3] = fmaf(cv, vv.w, accC[j4 + 3]);
      }
    }
    __syncthreads();
  }
  float* op = kvpart + (((size_t)chunk * 64 + n) * 128 + d) * 64 + mg;
#pragma unroll
  for (int j4 = 0; j4 < 16; j4 += 4) {
    *(float4*)(op + j4) = make_float4(accS[j4], accS[j4 + 1], accS[j4 + 2], accS[j4 + 3]);
    *(float4*)(op + 64 * 64 + j4) = make_float4(accC[j4], accC[j4 + 1], accC[j4 + 2], accC[j4 + 3]);
  }
}

__global__ void kv_reduce_kernel(const float* __restrict__ part, float* __restrict__ kv) {
  int i = blockIdx.x * 256 + threadIdx.x;
  float s = 0.f;
#pragma unroll
  for (int c = 0; c < 8; ++c) s += part[(size_t)c * (64 * 128 * 64) + i];
  kv[i] = s;
}

// ---------------------------------------------------------------------------
// out2[b][l][h*64+m] += sum_dd q2[t,n,l,dd]*kv[t,n,dd,m]
// ---------------------------------------------------------------------------
__global__ __launch_bounds__(256) void out_accum_kernel(
    const float* __restrict__ Qp, const float* __restrict__ kv,
    const float* __restrict__ sintab, const float* __restrict__ costab,
    float* __restrict__ out2) {
  int lc = blockIdx.x;
  int n = blockIdx.y;
  int b = n >> 3, h = n & 7;
  __shared__ float q2s[128][68];
  __shared__ float kvs[128][64];
  int tid = threadIdx.x;
  const float* kvn = kv + (size_t)n * 128 * 64;
#pragma unroll
  for (int i = 0; i < 8; ++i) {
    int idx = tid + i * 256;
    int dd = idx >> 4;
    int c4 = (idx & 15) * 4;
    *(float4*)&kvs[dd][c4] = *(const float4*)(kvn + (size_t)idx * 4);
  }
  int lane = tid & 63;
  int w = tid >> 6;
  int l0 = lc * 64;
  for (int i = 0; i < 16; ++i) {
    int lw = w + i * 4;
    int l = l0 + lw;
    float x = Qp[((size_t)b * L_DIM + l) * E_DIM + h * 64 + lane];
    float m = x;
#pragma unroll
    for (int off = 32; off > 0; off >>= 1) m = fmaxf(m, __shfl_xor(m, off));
    float e = __expf(x - m);
    float ssum = e;
#pragma unroll
    for (int off = 32; off > 0; off >>= 1) ssum += __shfl_xor(ssum, off);
    float p = e / ssum;
    q2s[lane][lw] = p * sintab[l];
    q2s[lane + 64][lw] = p * costab[l];
  }
  __syncthreads();
  int tl = tid >> 4;
  int tm = tid & 15;
  float acc[4][4];
#pragma unroll
  for (int i = 0; i < 4; ++i)
#pragma unroll
    for (int j = 0; j < 4; ++j) acc[i][j] = 0.f;
#pragma unroll 4
  for (int dd = 0; dd < 128; ++dd) {
    float4 a = *(const float4*)&q2s[dd][tl * 4];
    float4 bv = *(const float4*)&kvs[dd][tm * 4];
    acc[0][0] = fmaf(a.x, bv.x, acc[0][0]); acc[0][1] = fmaf(a.x, bv.y, acc[0][1]);
    acc[0][2] = fmaf(a.x, bv.z, acc[0][2]); acc[0][3] = fmaf(a.x, bv.w, acc[0][3]);
    acc[1][0] = fmaf(a.y, bv.x, acc[1][0]); acc[1][1] = fmaf(a.y, bv.y, acc[1][1]);
    acc[1][2] = fmaf(a.y, bv.z, acc[1][2]); acc[1][3] = fmaf(a.y, bv.w, acc[1][3]);
    acc[2][0] = fmaf(a.z, bv.x, acc[2][0]); acc[2][1] = fmaf(a.z, bv.y, acc[2][1]);
    acc[2][2] = fmaf(a.z, bv.z, acc[2][2]); acc[2][3] = fmaf(a.z, bv.w, acc[2][3]);
    acc[3][0] = fmaf(a.w, bv.x, acc[3][0]); acc[3][1] = fmaf(a.w, bv.y, acc[3][1]);
    acc[3][2] = fmaf(a.w, bv.z, acc[3][2]); acc[3][3] = fmaf(a.w, bv.w, acc[3][3]);
  }
#pragma unroll
  for (int i = 0; i < 4; ++i) {
    int l = l0 + tl * 4 + i;
    float* op = out2 + ((size_t)b * L_DIM + l) * E_DIM + h * 64 + tm * 4;
    float4 cur = *(float4*)op;
    cur.x += acc[i][0]; cur.y += acc[i][1]; cur.z += acc[i][2]; cur.w += acc[i][3];
    *(float4*)op = cur;
  }
}

// ---------------------------------------------------------------------------
extern "C" void kernel_launch(void* const* d_in, const int* in_sizes, int n_in,
                              void* d_out, int out_size, void* d_ws, size_t ws_size,
                              hipStream_t stream) {
  const float* query = (const float*)d_in[0];
  const float* key   = (const float*)d_in[1];
  const float* value = (const float*)d_in[2];
  const float* Wq    = (const float*)d_in[3];
  const float* bq    = (const float*)d_in[4];
  const float* Wk    = (const float*)d_in[5];
  const float* bk    = (const float*)d_in[6];
  const float* Wv    = (const float*)d_in[7];
  const float* bv    = (const float*)d_in[8];
  const float* Wout  = (const float*)d_in[9];
  const float* bout  = (const float*)d_in[10];
  float* out = (float*)d_out;
  float* ws = (float*)d_ws;

  const size_t F_PROJ   = 0;
  const size_t F_VOUT   = F_PROJ + 16777216;
  const size_t F_KVPART = F_VOUT + 16777216;
  const size_t F_KV     = F_KVPART + 4194304;
  const size_t F_CMAX   = F_KV + 1048576;
  const size_t F_CINV   = F_CMAX + 4096;
  const size_t F_SIN    = F_CINV + 4096;
  const size_t F_COS    = F_SIN + 4096;
  const size_t TOTALF   = F_COS + 4096;
  if (ws_size < TOTALF * sizeof(float)) {
    fprintf(stderr, "kernel_launch: ws too small (%zu < %zu)\n", ws_size, TOTALF * 4);
    return;
  }
  float* proj   = ws + F_PROJ;
  float* vout   = ws + F_VOUT;
  float* kvpart = ws + F_KVPART;
  float* kvbuf  = ws + F_KV;
  float* cmax   = ws + F_CMAX;
  float* cinv   = ws + F_CINV;
  float* sintab = ws + F_SIN;
  float* costab = ws + F_COS;
  // colstats partials alias the kvpart region (disjoint lifetime: consumed
  // by kcolstats_reduce before kv_partial_kernel writes kvpart)
  float* pmax = kvpart;
  float* psum = kvpart + 131072;

  sincos_kernel<<<16, 256, 0, stream>>>(sintab, costab);

  dim3 gemm_grid(M_ROWS / 128, 4);
  // V projection
  gemm_xwt_bf16<<<gemm_grid, 256, 0, stream>>>(value, Wv, bv, vout);

  // per-term: K-projection -> col softmax stats -> kv state
  for (int t = 0; t < T_DIM; ++t) {
    gemm_xwt_bf16<<<gemm_grid, 256, 0, stream>>>(key, Wk + (size_t)t * 512 * 512,
                                                 bk + t * 512, proj);
    kcolstats_part<<<dim3(8, 8, 32), dim3(64, 4), 0, stream>>>(proj, pmax, psum);
    kcolstats_reduce<<<16, 256, 0, stream>>>(pmax, psum, cmax, cinv);
    kv_partial_kernel<<<dim3(8, 64), 256, 0, stream>>>(proj, vout, cmax, cinv,
                                                       sintab, costab, kvpart);
    kv_reduce_kernel<<<2048, 256, 0, stream>>>(kvpart, kvbuf + (size_t)t * 524288);
  }
  // vproj dead; region becomes out2 accumulator
  hipMemsetAsync(vout, 0, 16777216 * sizeof(float), stream);
  for (int t = 0; t < T_DIM; ++t) {
    gemm_xwt_bf16<<<gemm_grid, 256, 0, stream>>>(query, Wq + (size_t)t * 512 * 512,
                                                 bq + t * 512, proj);
    out_accum_kernel<<<dim3(64, 64), 256, 0, stream>>>(proj, kvbuf + (size_t)t * 524288,
                                                       sintab, costab, vout);
  }
  // final output projection
  gemm_xwt_bf16<<<gemm_grid, 256, 0, stream>>>(vout, Wout, bout, out);
}